// Round 8
// baseline (600.422 us; speedup 1.0000x reference)
//
#include <hip/hip_runtime.h>

#define T_STEPS 512
#define IN_DIM 11
#define H_DIM 16
#define ROW_F (T_STEPS * IN_DIM)    // 5632 floats per batch row
#define LOG2E 1.44269504088896340736f

typedef float v2f __attribute__((ext_vector_type(2)));

// Packed fp32 FMA (v_pk_fma_f32): 2 MACs/instr, full rate. All-VGPR form.
__device__ __forceinline__ v2f pk_fma(v2f a, v2f b, v2f c) {
    v2f d;
    asm("v_pk_fma_f32 %0, %1, %2, %3" : "=v"(d) : "v"(a), "v"(b), "v"(c));
    return d;
}

// Packed fp32 FMA with the multiplicand pair in SGPRs (uniform h values).
// One 64-bit SGPR operand per VALU instr is allowed.
__device__ __forceinline__ v2f pk_fma_s(v2f a, v2f b_uniform, v2f c) {
    v2f d;
    asm("v_pk_fma_f32 %0, %1, %2, %3" : "=v"(d) : "v"(a), "s"(b_uniform), "v"(c));
    return d;
}

// DPP quad_perm broadcast within each group of 4 lanes (VALU pipe).
template<int CTRL>
__device__ __forceinline__ float qperm(float v) {
    return __builtin_bit_cast(float,
        __builtin_amdgcn_update_dpp(0, __builtin_bit_cast(int, v),
                                    CTRL, 0xf, 0xf, true));
}

// v_readlane: uniform (SGPR) result = v[lane L]. VALU pipe, short latency.
template<int L>
__device__ __forceinline__ float rdl(float v) {
    return __builtin_bit_cast(float,
        __builtin_amdgcn_readlane(__builtin_bit_cast(int, v), L));
}

__device__ __forceinline__ float bcast_lane(float v, int l) {
    return __builtin_bit_cast(float,
        __builtin_amdgcn_readlane(__builtin_bit_cast(int, v), l));
}

// Wave-uniform h gather: lane 4r holds h[r]; 16 readlanes -> 8 SGPR pairs.
// Replaces the LDS slab write+read round trip (~130cy on the serial chain)
// with independent VALU ops (~10cy). h state lives in SGPRs.
#define GATHER_H(hv, hs)                                  \
    {                                                     \
        hs[0] = (v2f){rdl<0>(hv),  rdl<4>(hv)};           \
        hs[1] = (v2f){rdl<8>(hv),  rdl<12>(hv)};          \
        hs[2] = (v2f){rdl<16>(hv), rdl<20>(hv)};          \
        hs[3] = (v2f){rdl<24>(hv), rdl<28>(hv)};          \
        hs[4] = (v2f){rdl<32>(hv), rdl<36>(hv)};          \
        hs[5] = (v2f){rdl<40>(hv), rdl<44>(hv)};          \
        hs[6] = (v2f){rdl<48>(hv), rdl<52>(hv)};          \
        hs[7] = (v2f){rdl<56>(hv), rdl<60>(hv)};          \
    }

// LSTM activation step: gsum -> gate act -> quad gate bcast -> cell -> h out.
#define ACT_STEP(gsum, cst, hv_out)                                           \
    {                                                                         \
        const float a_ = __builtin_fmaf(vAa,                                  \
            __builtin_amdgcn_rcpf(1.0f + __builtin_amdgcn_exp2f(gsum)), vBc); \
        const float gi_ = qperm<0x00>(a_);                                    \
        const float gf_ = qperm<0x55>(a_);                                    \
        const float gg_ = qperm<0xAA>(a_);                                    \
        const float go_ = qperm<0xFF>(a_);                                    \
        cst = __builtin_fmaf(gf_, cst, gi_ * gg_);                            \
        const float tc_ = __builtin_fmaf(2.0f,                                \
            __builtin_amdgcn_rcpf(1.0f +                                      \
                __builtin_amdgcn_exp2f(-2.0f * LOG2E * cst)), -1.0f);         \
        hv_out = go_ * tc_;                                                   \
    }

// FUSED 2-layer LSTM, one wave per batch, ZERO-LDS recurrence.
// ROUND-7 POST-MORTEM: chain-latency bound at ~512 cyc/wave-step (real
// issue util ~33%; VALUBusy x dur ~ const across R1/R6/R7). Dominant chain
// element: LDS h-broadcast round trip (~130cy x2/step). Also VGPR_Count=56
// < working set -> compiler parked weights in AGPRs (accvgpr_read on hot
// path). Fix: h gathered to SGPRs via 16 v_readlane (VALU, independent),
// consumed by v_pk_fma_f32 with one SGPR-pair operand. Chain ~512 -> ~180
// cy; h state -> SGPRs frees 32 VGPRs (fits arch file, no AGPR); LDS = 0.
// x read via wave-uniform s_load (scalar pipe, R7 path, off the VALU).
__global__ __launch_bounds__(256, 4) void lstm2_head(
    const float* __restrict__ x,
    const float* __restrict__ Wih1, const float* __restrict__ Whh1,
    const float* __restrict__ bih1, const float* __restrict__ bhh1,
    const float* __restrict__ Wih2, const float* __restrict__ Whh2,
    const float* __restrict__ bih2, const float* __restrict__ bhh2,
    const float* __restrict__ Wd1, const float* __restrict__ bd1,
    const float* __restrict__ Wd2, const float* __restrict__ bd2,
    const float* __restrict__ Wd3, const float* __restrict__ bd3,
    float* __restrict__ out)
{
    const int lane = threadIdx.x & 63;
    const int wid = __builtin_amdgcn_readfirstlane((int)(threadIdx.x >> 6));
    const int b = blockIdx.x * 4 + wid;

    const int r   = lane >> 2;          // hidden index 0..15
    const int gt  = lane & 3;           // 0:i 1:f 2:g(tanh) 3:o
    const int row = gt * H_DIM + r;     // row in packed 4H weights

    const bool is_t = (gt == 2);
    const float M   = is_t ? (-2.0f * LOG2E) : (-LOG2E);
    const float vAa = is_t ? 2.0f : 1.0f;
    const float vBc = is_t ? -1.0f : 0.0f;

    // ---- per-lane weights (M-scaled), pinned in VGPRs ----
    float wx[IN_DIM];                   // layer-1 input weights (scalar x-dot)
    #pragma unroll
    for (int k = 0; k < IN_DIM; ++k) wx[k] = M * Wih1[row * IN_DIM + k];
    v2f wh1p[8], wi2p[8], wh2p[8];
    #pragma unroll
    for (int j = 0; j < 8; ++j) {
        wh1p[j] = (v2f){M * Whh1[row * H_DIM + 2 * j], M * Whh1[row * H_DIM + 2 * j + 1]};
        wi2p[j] = (v2f){M * Wih2[row * H_DIM + 2 * j], M * Wih2[row * H_DIM + 2 * j + 1]};
        wh2p[j] = (v2f){M * Whh2[row * H_DIM + 2 * j], M * Whh2[row * H_DIM + 2 * j + 1]};
    }
    const float bb1 = M * (bih1[row] + bhh1[row]);
    const float bb2 = M * (bih2[row] + bhh2[row]);
    #pragma unroll
    for (int k = 0; k < IN_DIM; ++k) asm volatile("" : "+v"(wx[k]));
    #pragma unroll
    for (int j = 0; j < 8; ++j) {
        asm volatile("" : "+v"(wh1p[j]));
        asm volatile("" : "+v"(wi2p[j]));
        asm volatile("" : "+v"(wh2p[j]));
    }

    const float* __restrict__ xb = x + (size_t)b * ROW_F;   // wave-uniform base

    float c1 = 0.f, c2 = 0.f, h2v = 0.f, ssum = 0.f;
    v2f h1s[8], h2s[8];                 // uniform h pairs (SGPRs)
    #pragma unroll
    for (int j = 0; j < 8; ++j) { h1s[j] = (v2f){0.f, 0.f}; h2s[j] = (v2f){0.f, 0.f}; }

    #pragma unroll 4
    for (int t = 0; t < T_STEPS; ++t) {
        const float* __restrict__ xr = xb + t * IN_DIM;     // uniform -> s_load

        // ---- layer-1 x-dot (uniform operands), two chains, bias folded ----
        float xs0 = __builtin_fmaf(wx[0], xr[0], bb1);
        float xs1 = wx[1] * xr[1];
        xs0 = __builtin_fmaf(wx[2], xr[2], xs0);
        xs1 = __builtin_fmaf(wx[3], xr[3], xs1);
        xs0 = __builtin_fmaf(wx[4], xr[4], xs0);
        xs1 = __builtin_fmaf(wx[5], xr[5], xs1);
        xs0 = __builtin_fmaf(wx[6], xr[6], xs0);
        xs1 = __builtin_fmaf(wx[7], xr[7], xs1);
        xs0 = __builtin_fmaf(wx[8], xr[8], xs0);
        xs1 = __builtin_fmaf(wx[9], xr[9], xs1);
        xs0 = __builtin_fmaf(wx[10], xr[10], xs0);

        // ---- layer-2 recurrent dot (h2s uniform from prev step) ----
        v2f a2p = pk_fma_s(wh2p[0], h2s[0], (v2f){bb2, 0.f});
        v2f a2q = pk_fma_s(wh2p[1], h2s[1], (v2f){0.f, 0.f});
        #pragma unroll
        for (int j = 2; j < 8; j += 2) {
            a2p = pk_fma_s(wh2p[j],     h2s[j],     a2p);
            a2q = pk_fma_s(wh2p[j + 1], h2s[j + 1], a2q);
        }

        // ---- layer-1 recurrent dot, x-dot folded into accumulator init ----
        v2f a1p = pk_fma_s(wh1p[0], h1s[0], (v2f){xs0, xs1});
        v2f a1q = pk_fma_s(wh1p[1], h1s[1], (v2f){0.f, 0.f});
        #pragma unroll
        for (int j = 2; j < 8; j += 2) {
            a1p = pk_fma_s(wh1p[j],     h1s[j],     a1p);
            a1q = pk_fma_s(wh1p[j + 1], h1s[j + 1], a1q);
        }

        const v2f s1 = a1p + a1q;
        const float g1 = s1.x + s1.y;
        float h1v;
        ACT_STEP(g1, c1, h1v);
        GATHER_H(h1v, h1s);             // 16 readlane -> SGPR pairs

        #pragma unroll
        for (int j = 0; j < 8; j += 2) {
            a2p = pk_fma_s(wi2p[j],     h1s[j],     a2p);
            a2q = pk_fma_s(wi2p[j + 1], h1s[j + 1], a2q);
        }

        const v2f s2 = a2p + a2q;
        const float g2 = s2.x + s2.y;
        ACT_STEP(g2, c2, h2v);
        GATHER_H(h2v, h2s);

        ssum += __builtin_amdgcn_exp2f(LOG2E * h2v);
    }

    // s[b,k] = exp(h2[T-1,k]) / sum_t exp(h2[t,k]); h2v replicated per quad.
    const float sv = __builtin_amdgcn_exp2f(LOG2E * h2v) / ssum;

    float ssb[H_DIM];
    #pragma unroll
    for (int k = 0; k < H_DIM; ++k) ssb[k] = bcast_lane(sv, 4 * k);

    // Dense head 16 -> 8 -> 8 -> 3 + softmax (one-time epilogue).
    const int r8 = lane & 7;
    float acc1 = bd1[r8];
    #pragma unroll
    for (int k = 0; k < H_DIM; ++k)
        acc1 = __builtin_fmaf(Wd1[r8 * H_DIM + k], ssb[k], acc1);

    float d1s[8];
    #pragma unroll
    for (int j = 0; j < 8; ++j) d1s[j] = bcast_lane(acc1, j);

    float acc2 = bd2[r8];
    #pragma unroll
    for (int k = 0; k < 8; ++k)
        acc2 = __builtin_fmaf(Wd2[r8 * 8 + k], d1s[k], acc2);

    float d2s[8];
    #pragma unroll
    for (int j = 0; j < 8; ++j) d2s[j] = bcast_lane(acc2, j);

    float lg = 0.f;
    if (lane < 3) {
        lg = bd3[lane];
        #pragma unroll
        for (int k = 0; k < 8; ++k)
            lg = __builtin_fmaf(Wd3[lane * 8 + k], d2s[k], lg);
    }
    const float l0 = bcast_lane(lg, 0);
    const float l1 = bcast_lane(lg, 1);
    const float l2 = bcast_lane(lg, 2);
    const float mx = fmaxf(l0, fmaxf(l1, l2));
    const float e0 = __builtin_amdgcn_exp2f(LOG2E * (l0 - mx));
    const float e1 = __builtin_amdgcn_exp2f(LOG2E * (l1 - mx));
    const float e2 = __builtin_amdgcn_exp2f(LOG2E * (l2 - mx));
    const float inv = 1.0f / (e0 + e1 + e2);
    if (lane < 3) {
        const float ev = (lane == 0) ? e0 : ((lane == 1) ? e1 : e2);
        out[b * 3 + lane] = ev * inv;
    }
}

extern "C" void kernel_launch(void* const* d_in, const int* in_sizes, int n_in,
                              void* d_out, int out_size, void* d_ws, size_t ws_size,
                              hipStream_t stream) {
    (void)in_sizes; (void)n_in; (void)out_size; (void)d_ws; (void)ws_size;
    const float* x    = (const float*)d_in[0];
    const float* Wih1 = (const float*)d_in[1];
    const float* Whh1 = (const float*)d_in[2];
    const float* bih1 = (const float*)d_in[3];
    const float* bhh1 = (const float*)d_in[4];
    const float* Wih2 = (const float*)d_in[5];
    const float* Whh2 = (const float*)d_in[6];
    const float* bih2 = (const float*)d_in[7];
    const float* bhh2 = (const float*)d_in[8];
    const float* Wd1  = (const float*)d_in[9];
    const float* bd1  = (const float*)d_in[10];
    const float* Wd2  = (const float*)d_in[11];
    const float* bd2  = (const float*)d_in[12];
    const float* Wd3  = (const float*)d_in[13];
    const float* bd3  = (const float*)d_in[14];

    lstm2_head<<<dim3(4096 / 4), dim3(256), 0, stream>>>(
        x, Wih1, Whh1, bih1, bhh1, Wih2, Whh2, bih2, bhh2,
        Wd1, bd1, Wd2, bd2, Wd3, bd3, (float*)d_out);
}

// Round 9
// 499.283 us; speedup vs baseline: 1.2026x; 1.2026x over previous
//
#include <hip/hip_runtime.h>

#define T_STEPS 512
#define IN_DIM 11
#define ROW_PAD 12                  // x row padded to 12 floats in LDS
#define H_DIM 16
#define ROW_F (T_STEPS * IN_DIM)    // 5632 floats per batch row
#define CHUNK_T 16                  // t-steps per x chunk
#define CHUNK_F (CHUNK_T * IN_DIM)  // 176 source floats per chunk
#define N_CHUNK (T_STEPS / CHUNK_T)
#define NB 2                        // batches per wave (software dual-issue)
#define LOG2E 1.44269504088896340736f

typedef float v2f __attribute__((ext_vector_type(2)));
typedef float v4f __attribute__((ext_vector_type(4)));

// Packed fp32 FMA (v_pk_fma_f32): 2 MACs/instr, full rate.
__device__ __forceinline__ v2f pk_fma(v2f a, v2f b, v2f c) {
    v2f d;
    asm("v_pk_fma_f32 %0, %1, %2, %3" : "=v"(d) : "v"(a), "v"(b), "v"(c));
    return d;
}

// DPP quad_perm broadcast within each group of 4 lanes (VALU pipe).
template<int CTRL>
__device__ __forceinline__ float qperm(float v) {
    return __builtin_bit_cast(float,
        __builtin_amdgcn_update_dpp(0, __builtin_bit_cast(int, v),
                                    CTRL, 0xf, 0xf, true));
}

__device__ __forceinline__ float bcast_lane(float v, int l) {
    return __builtin_bit_cast(float,
        __builtin_amdgcn_readlane(__builtin_bit_cast(int, v), l));
}

// LSTM activation step: gsum -> gate act -> quad gate bcast -> cell -> h out.
#define ACT_STEP(gsum, cst, hv_out)                                           \
    {                                                                         \
        const float a_ = __builtin_fmaf(vAa,                                  \
            __builtin_amdgcn_rcpf(1.0f + __builtin_amdgcn_exp2f(gsum)), vBc); \
        const float gi_ = qperm<0x00>(a_);                                    \
        const float gf_ = qperm<0x55>(a_);                                    \
        const float gg_ = qperm<0xAA>(a_);                                    \
        const float go_ = qperm<0xFF>(a_);                                    \
        cst = __builtin_fmaf(gf_, cst, gi_ * gg_);                            \
        const float tc_ = __builtin_fmaf(2.0f,                                \
            __builtin_amdgcn_rcpf(1.0f +                                      \
                __builtin_amdgcn_exp2f(-2.0f * LOG2E * cst)), -1.0f);         \
        hv_out = go_ * tc_;                                                   \
    }

// FUSED 2-layer LSTM, TWO batches per wave (software dual-issue).
// ROUND-8 POST-MORTEM: R1 (390us) still best; wall 1830cy/step vs single
// -chain ~460cy with ~2.75 waves/SIMD resident => HW wave scheduler gives
// near-ZERO mutual latency hiding (4x460 ~= 1830, convoying). All prior
// rounds reshuffled one chain; none raised per-wave concurrency. Fix:
// carry NB=2 independent batches per wave. Weights SHARED (60 VGPRs serve
// both); state duplicated; straight-line unrolled body lets the compile-
// time scheduler interleave the two chains deterministically (B's dots
// issue inside A's ACT/LDS stalls). launch_bounds(256,2): 256-reg budget,
// grid 512 blocks = 8 waves/CU (grid-capped) so occupancy unaffected.
// All [NB] arrays indexed by fully-unrolled bi (constant indices only).
__global__ __launch_bounds__(256, 2) void lstm2_head(
    const float* __restrict__ x,
    const float* __restrict__ Wih1, const float* __restrict__ Whh1,
    const float* __restrict__ bih1, const float* __restrict__ bhh1,
    const float* __restrict__ Wih2, const float* __restrict__ Whh2,
    const float* __restrict__ bih2, const float* __restrict__ bhh2,
    const float* __restrict__ Wd1, const float* __restrict__ bd1,
    const float* __restrict__ Wd2, const float* __restrict__ bd2,
    const float* __restrict__ Wd3, const float* __restrict__ bd3,
    float* __restrict__ out)
{
    __shared__ alignas(16) float xlds[4][NB][2][212];        // x chunks, dbuf
    __shared__ alignas(16) float shh[4][NB][2][H_DIM];       // h slabs

    const int lane = threadIdx.x & 63;
    const int wid = __builtin_amdgcn_readfirstlane((int)(threadIdx.x >> 6));
    const int b0 = blockIdx.x * (4 * NB) + wid * NB;

    const int r   = lane >> 2;          // hidden index 0..15
    const int gt  = lane & 3;           // 0:i 1:f 2:g(tanh) 3:o
    const int row = gt * H_DIM + r;     // row in packed 4H weights

    const bool is_t = (gt == 2);
    const float M   = is_t ? (-2.0f * LOG2E) : (-LOG2E);
    const float vAa = is_t ? 2.0f : 1.0f;
    const float vBc = is_t ? -1.0f : 0.0f;

    // ---- SHARED per-lane weights (M-scaled), pinned; serve both batches ----
    v2f wi1p[6], wh1p[8], wi2p[8], wh2p[8];
    #pragma unroll
    for (int j = 0; j < 5; ++j)
        wi1p[j] = (v2f){M * Wih1[row * IN_DIM + 2 * j], M * Wih1[row * IN_DIM + 2 * j + 1]};
    wi1p[5] = (v2f){M * Wih1[row * IN_DIM + 10], 0.0f};   // pad weight = 0
    #pragma unroll
    for (int j = 0; j < 8; ++j) {
        wh1p[j] = (v2f){M * Whh1[row * H_DIM + 2 * j], M * Whh1[row * H_DIM + 2 * j + 1]};
        wi2p[j] = (v2f){M * Wih2[row * H_DIM + 2 * j], M * Wih2[row * H_DIM + 2 * j + 1]};
        wh2p[j] = (v2f){M * Whh2[row * H_DIM + 2 * j], M * Whh2[row * H_DIM + 2 * j + 1]};
    }
    const float bb1 = M * (bih1[row] + bhh1[row]);
    const float bb2 = M * (bih2[row] + bhh2[row]);
    #pragma unroll
    for (int j = 0; j < 6; ++j) asm volatile("" : "+v"(wi1p[j]));
    #pragma unroll
    for (int j = 0; j < 8; ++j) {
        asm volatile("" : "+v"(wh1p[j]));
        asm volatile("" : "+v"(wi2p[j]));
        asm volatile("" : "+v"(wh2p[j]));
    }

    // per-batch x base pointers (wave-uniform)
    const float* __restrict__ xb[NB];
    #pragma unroll
    for (int bi = 0; bi < NB; ++bi) xb[bi] = x + (size_t)(b0 + bi) * ROW_F;

    // h slab pointers per batch
    float* hs1[NB]; float* hs2[NB];
    const v4f* h1q4[NB]; const v4f* h2q4[NB];
    #pragma unroll
    for (int bi = 0; bi < NB; ++bi) {
        hs1[bi] = &shh[wid][bi][0][0];
        hs2[bi] = &shh[wid][bi][1][0];
        h1q4[bi] = (const v4f*)hs1[bi];
        h2q4[bi] = (const v4f*)hs2[bi];
    }

    // zero x pad slots (slot 11 of each of 16 rows, both buffers, both batches)
    if (lane < 32) {
        const int buf = lane >> 4, rr = lane & 15;
        xlds[wid][0][buf][rr * ROW_PAD + IN_DIM] = 0.0f;
        xlds[wid][1][buf][rr * ROW_PAD + IN_DIM] = 0.0f;
    }

    // staging offsets: source float f -> padded slot (f/11)*12 + f%11
    const int f1i = lane, f2i = lane + 64, f3i = lane + 128;
    const int p1 = (f1i / IN_DIM) * ROW_PAD + (f1i % IN_DIM);
    const int p2 = (f2i / IN_DIM) * ROW_PAD + (f2i % IN_DIM);
    const int p3 = (f3i / IN_DIM) * ROW_PAD + (f3i % IN_DIM);

    // prologue: global-load chunk 0 for both batches
    float gl0[NB], gl1[NB], gl2[NB];
    #pragma unroll
    for (int bi = 0; bi < NB; ++bi) {
        gl0[bi] = xb[bi][f1i];
        gl1[bi] = xb[bi][f2i];
        gl2[bi] = xb[bi][min(f3i, ROW_F - 1)];
    }

    float c1[NB], c2[NB], h2v[NB], ssum[NB];
    v2f h1r[NB][8], h2r[NB][8];
    #pragma unroll
    for (int bi = 0; bi < NB; ++bi) {
        c1[bi] = 0.f; c2[bi] = 0.f; h2v[bi] = 0.f; ssum[bi] = 0.f;
        #pragma unroll
        for (int j = 0; j < 8; ++j) {
            h1r[bi][j] = (v2f){0.f, 0.f};
            h2r[bi][j] = (v2f){0.f, 0.f};
        }
    }

    for (int ck = 0; ck < N_CHUNK; ++ck) {
        float* xbuf[NB];
        #pragma unroll
        for (int bi = 0; bi < NB; ++bi) {
            xbuf[bi] = &xlds[wid][bi][ck & 1][0];
            xbuf[bi][p1] = gl0[bi];
            xbuf[bi][p2] = gl1[bi];
            xbuf[bi][p3] = gl2[bi];
        }
        if (ck + 1 < N_CHUNK) {
            const int base = (ck + 1) * CHUNK_F;
            #pragma unroll
            for (int bi = 0; bi < NB; ++bi) {
                gl0[bi] = xb[bi][base + f1i];
                gl1[bi] = xb[bi][base + f2i];
                gl2[bi] = xb[bi][min(base + f3i, ROW_F - 1)];
            }
        }

        #pragma unroll
        for (int t2 = 0; t2 < CHUNK_T; ++t2) {
            v2f a2p[NB], a2q[NB], a1p[NB], a1q[NB];

            // ---- layer-2 recurrent dots (both batches, interleaved) ----
            #pragma unroll
            for (int bi = 0; bi < NB; ++bi) {
                a2p[bi] = pk_fma(wh2p[0], h2r[bi][0], (v2f){bb2, 0.f});
                a2q[bi] = pk_fma(wh2p[1], h2r[bi][1], (v2f){0.f, 0.f});
                #pragma unroll
                for (int j = 2; j < 8; j += 2) {
                    a2p[bi] = pk_fma(wh2p[j],     h2r[bi][j],     a2p[bi]);
                    a2q[bi] = pk_fma(wh2p[j + 1], h2r[bi][j + 1], a2q[bi]);
                }
            }

            // ---- layer-1 preact: x-dot (LDS pairs) + recurrent (regs) ----
            #pragma unroll
            for (int bi = 0; bi < NB; ++bi) {
                const v2f* const xr = (const v2f*)(xbuf[bi] + t2 * ROW_PAD);
                a1p[bi] = pk_fma(wi1p[0], xr[0], (v2f){bb1, 0.f});
                a1q[bi] = pk_fma(wi1p[1], xr[1], (v2f){0.f, 0.f});
                #pragma unroll
                for (int j = 2; j < 6; j += 2) {
                    a1p[bi] = pk_fma(wi1p[j],     xr[j],     a1p[bi]);
                    a1q[bi] = pk_fma(wi1p[j + 1], xr[j + 1], a1q[bi]);
                }
                #pragma unroll
                for (int j = 0; j < 8; j += 2) {
                    a1p[bi] = pk_fma(wh1p[j],     h1r[bi][j],     a1p[bi]);
                    a1q[bi] = pk_fma(wh1p[j + 1], h1r[bi][j + 1], a1q[bi]);
                }
            }

            // ---- layer-1 activation + h1 slab round trip ----
            float h1v[NB];
            #pragma unroll
            for (int bi = 0; bi < NB; ++bi) {
                const v2f s1 = a1p[bi] + a1q[bi];
                const float g1 = s1.x + s1.y;
                ACT_STEP(g1, c1[bi], h1v[bi]);
                hs1[bi][r] = h1v[bi];               // quad-replicated write
            }
            #pragma unroll
            for (int bi = 0; bi < NB; ++bi) {
                #pragma unroll
                for (int j = 0; j < 4; ++j) {
                    const v4f q = h1q4[bi][j];
                    h1r[bi][2 * j]     = (v2f){q.x, q.y};
                    h1r[bi][2 * j + 1] = (v2f){q.z, q.w};
                }
            }

            // ---- layer-2 input dot on fresh h1 ----
            #pragma unroll
            for (int bi = 0; bi < NB; ++bi) {
                #pragma unroll
                for (int j = 0; j < 8; j += 2) {
                    a2p[bi] = pk_fma(wi2p[j],     h1r[bi][j],     a2p[bi]);
                    a2q[bi] = pk_fma(wi2p[j + 1], h1r[bi][j + 1], a2q[bi]);
                }
            }

            // ---- layer-2 activation + h2 slab round trip + softmax accum ----
            #pragma unroll
            for (int bi = 0; bi < NB; ++bi) {
                const v2f s2 = a2p[bi] + a2q[bi];
                const float g2 = s2.x + s2.y;
                ACT_STEP(g2, c2[bi], h2v[bi]);
                hs2[bi][r] = h2v[bi];
            }
            #pragma unroll
            for (int bi = 0; bi < NB; ++bi) {
                #pragma unroll
                for (int j = 0; j < 4; ++j) {
                    const v4f q = h2q4[bi][j];
                    h2r[bi][2 * j]     = (v2f){q.x, q.y};
                    h2r[bi][2 * j + 1] = (v2f){q.z, q.w};
                }
                ssum[bi] += __builtin_amdgcn_exp2f(LOG2E * h2v[bi]);
            }
        }
    }

    // ---- epilogue per batch: time-softmax select + dense head ----
    #pragma unroll
    for (int bi = 0; bi < NB; ++bi) {
        const int b = b0 + bi;
        const float sv = __builtin_amdgcn_exp2f(LOG2E * h2v[bi]) / ssum[bi];

        float ssb[H_DIM];
        #pragma unroll
        for (int k = 0; k < H_DIM; ++k) ssb[k] = bcast_lane(sv, 4 * k);

        const int r8 = lane & 7;
        float acc1 = bd1[r8];
        #pragma unroll
        for (int k = 0; k < H_DIM; ++k)
            acc1 = __builtin_fmaf(Wd1[r8 * H_DIM + k], ssb[k], acc1);

        float d1s[8];
        #pragma unroll
        for (int j = 0; j < 8; ++j) d1s[j] = bcast_lane(acc1, j);

        float acc2 = bd2[r8];
        #pragma unroll
        for (int k = 0; k < 8; ++k)
            acc2 = __builtin_fmaf(Wd2[r8 * 8 + k], d1s[k], acc2);

        float d2s[8];
        #pragma unroll
        for (int j = 0; j < 8; ++j) d2s[j] = bcast_lane(acc2, j);

        float lg = 0.f;
        if (lane < 3) {
            lg = bd3[lane];
            #pragma unroll
            for (int k = 0; k < 8; ++k)
                lg = __builtin_fmaf(Wd3[lane * 8 + k], d2s[k], lg);
        }
        const float l0 = bcast_lane(lg, 0);
        const float l1 = bcast_lane(lg, 1);
        const float l2 = bcast_lane(lg, 2);
        const float mx = fmaxf(l0, fmaxf(l1, l2));
        const float e0 = __builtin_amdgcn_exp2f(LOG2E * (l0 - mx));
        const float e1 = __builtin_amdgcn_exp2f(LOG2E * (l1 - mx));
        const float e2 = __builtin_amdgcn_exp2f(LOG2E * (l2 - mx));
        const float inv = 1.0f / (e0 + e1 + e2);
        if (lane < 3) {
            const float ev = (lane == 0) ? e0 : ((lane == 1) ? e1 : e2);
            out[b * 3 + lane] = ev * inv;
        }
    }
}

extern "C" void kernel_launch(void* const* d_in, const int* in_sizes, int n_in,
                              void* d_out, int out_size, void* d_ws, size_t ws_size,
                              hipStream_t stream) {
    (void)in_sizes; (void)n_in; (void)out_size; (void)d_ws; (void)ws_size;
    const float* x    = (const float*)d_in[0];
    const float* Wih1 = (const float*)d_in[1];
    const float* Whh1 = (const float*)d_in[2];
    const float* bih1 = (const float*)d_in[3];
    const float* bhh1 = (const float*)d_in[4];
    const float* Wih2 = (const float*)d_in[5];
    const float* Whh2 = (const float*)d_in[6];
    const float* bih2 = (const float*)d_in[7];
    const float* bhh2 = (const float*)d_in[8];
    const float* Wd1  = (const float*)d_in[9];
    const float* bd1  = (const float*)d_in[10];
    const float* Wd2  = (const float*)d_in[11];
    const float* bd2  = (const float*)d_in[12];
    const float* Wd3  = (const float*)d_in[13];
    const float* bd3  = (const float*)d_in[14];

    lstm2_head<<<dim3(4096 / (4 * NB)), dim3(256), 0, stream>>>(
        x, Wih1, Whh1, bih1, bhh1, Wih2, Whh2, bih2, bhh2,
        Wd1, bd1, Wd2, bd2, Wd3, bd3, (float*)d_out);
}

// Round 10
// 491.962 us; speedup vs baseline: 1.2205x; 1.0149x over previous
//
#include <hip/hip_runtime.h>

#define T_STEPS 512
#define IN_DIM 11
#define ROW_PAD 16                  // x row padded to 16 floats (one b128 per quad lane)
#define H_DIM 16
#define ROW_F (T_STEPS * IN_DIM)    // 5632 floats per batch row
#define CHUNK_T 16                  // t-steps per x chunk
#define CHUNK_F (CHUNK_T * IN_DIM)  // 176 source floats per chunk
#define N_CHUNK (T_STEPS / CHUNK_T)
#define NB 2                        // batches per wave (software dual-issue)
#define LOG2E 1.44269504088896340736f

typedef float v2f __attribute__((ext_vector_type(2)));
typedef float v4f __attribute__((ext_vector_type(4)));

// Packed fp32 FMA (v_pk_fma_f32): 2 MACs/instr, full rate.
__device__ __forceinline__ v2f pk_fma(v2f a, v2f b, v2f c) {
    v2f d;
    asm("v_pk_fma_f32 %0, %1, %2, %3" : "=v"(d) : "v"(a), "v"(b), "v"(c));
    return d;
}

// DPP quad_perm within each group of 4 lanes (VALU pipe, NOT LDS).
template<int CTRL>
__device__ __forceinline__ float qperm(float v) {
    return __builtin_bit_cast(float,
        __builtin_amdgcn_update_dpp(0, __builtin_bit_cast(int, v),
                                    CTRL, 0xf, 0xf, true));
}
// xor-exchange within quad: lane^1=0xB1, lane^2=0x4E, lane^3=0x1B

__device__ __forceinline__ float bcast_lane(float v, int l) {
    return __builtin_bit_cast(float,
        __builtin_amdgcn_readlane(__builtin_bit_cast(int, v), l));
}

// LSTM activation step: gsum -> gate act -> quad gate bcast -> cell -> h out.
#define ACT_STEP(gsum, cst, hv_out)                                           \
    {                                                                         \
        const float a_ = __builtin_fmaf(vAa,                                  \
            __builtin_amdgcn_rcpf(1.0f + __builtin_amdgcn_exp2f(gsum)), vBc); \
        const float gi_ = qperm<0x00>(a_);                                    \
        const float gf_ = qperm<0x55>(a_);                                    \
        const float gg_ = qperm<0xAA>(a_);                                    \
        const float go_ = qperm<0xFF>(a_);                                    \
        cst = __builtin_fmaf(gf_, cst, gi_ * gg_);                            \
        const float tc_ = __builtin_fmaf(2.0f,                                \
            __builtin_amdgcn_rcpf(1.0f +                                      \
                __builtin_amdgcn_exp2f(-2.0f * LOG2E * cst)), -1.0f);         \
        hv_out = go_ * tc_;                                                   \
    }

// QUAD-SPLIT x NB=2: 2-layer LSTM, two batches per wave.
// ROUND-9 POST-MORTEM (quantitative): chains/SIMD is ALWAYS 4; the binding
// resource in the fused family is the per-CU LDS pipe (R1: 16 waves x ~140
// cyc ~ 2240 est vs 1830 wall; R9: 8 x ~290 ~ 2320 vs 2190 - both match).
// R6's quad-split cut LDS to ~760 cyc/CU-step but was 1-chain/wave ->
// chain-latency bound. This round combines them: quad-split dots (5 LDS
// ops/batch-step: 1 b128 x-read, 2 b32 h-writes, 2 b128 h-reads) + NB=2
// (weights shared, two independent chains interleaved at compile time).
// Est: LDS ~760, issue ~600, chain hidden -> ~800 cyc/step ~ 170us.
// ALSO fixes R6's latent OOB: staging store index p3 is now computed from
// the CLAMPED chunk index (was unclamped -> wrote up to +20 floats past
// the 256-float buffer into the next wave's region).
// Lane (r,gt): partials for rows (gt^j)*16+r over k in {4gt..4gt+3};
// 3 qperm xor-exchanges complete each row's 16-dot on the VALU pipe.
__global__ __launch_bounds__(256, 2) void lstm2_head(
    const float* __restrict__ x,
    const float* __restrict__ Wih1, const float* __restrict__ Whh1,
    const float* __restrict__ bih1, const float* __restrict__ bhh1,
    const float* __restrict__ Wih2, const float* __restrict__ Whh2,
    const float* __restrict__ bih2, const float* __restrict__ bhh2,
    const float* __restrict__ Wd1, const float* __restrict__ bd1,
    const float* __restrict__ Wd2, const float* __restrict__ bd2,
    const float* __restrict__ Wd3, const float* __restrict__ bd3,
    float* __restrict__ out)
{
    __shared__ alignas(16) float xlds[4][NB][2][CHUNK_T * ROW_PAD]; // 16 KB
    __shared__ alignas(16) float shh[4][NB][2][H_DIM];              // 1 KB

    const int lane = threadIdx.x & 63;
    const int wid = __builtin_amdgcn_readfirstlane((int)(threadIdx.x >> 6));
    const int b0 = blockIdx.x * (4 * NB) + wid * NB;

    const int r   = lane >> 2;          // hidden index 0..15
    const int gt  = lane & 3;           // 0:i 1:f 2:g(tanh) 3:o
    const int row = gt * H_DIM + r;     // this lane's output row in 4H

    const bool is_t = (gt == 2);
    const float vAa = is_t ? 2.0f : 1.0f;
    const float vBc = is_t ? -1.0f : 0.0f;
    const float Mown = is_t ? (-2.0f * LOG2E) : (-LOG2E);

    // ---- quad-split weights (SHARED by both batches): for j=0..3,
    //      target row (gt^j)*16+r, k-quartet {4gt..4gt+3}, TARGET row's M ----
    v2f w1h[4][2], w1x[4][2], w2h[4][2], w2i[4][2];
    #pragma unroll
    for (int j = 0; j < 4; ++j) {
        const int gj = gt ^ j;
        const float Mj = (gj == 2) ? (-2.0f * LOG2E) : (-LOG2E);
        const int rowj = gj * H_DIM + r;
        #pragma unroll
        for (int i2 = 0; i2 < 2; ++i2) {
            const int k0 = 4 * gt + 2 * i2, k1 = k0 + 1;
            w1h[j][i2] = (v2f){Mj * Whh1[rowj * H_DIM + k0],
                               Mj * Whh1[rowj * H_DIM + k1]};
            w1x[j][i2] = (v2f){k0 < IN_DIM ? Mj * Wih1[rowj * IN_DIM + k0] : 0.f,
                               k1 < IN_DIM ? Mj * Wih1[rowj * IN_DIM + k1] : 0.f};
            w2h[j][i2] = (v2f){Mj * Whh2[rowj * H_DIM + k0],
                               Mj * Whh2[rowj * H_DIM + k1]};
            w2i[j][i2] = (v2f){Mj * Wih2[rowj * H_DIM + k0],
                               Mj * Wih2[rowj * H_DIM + k1]};
        }
    }
    const float bb1 = Mown * (bih1[row] + bhh1[row]);
    const float bb2 = Mown * (bih2[row] + bhh2[row]);
    #pragma unroll
    for (int j = 0; j < 4; ++j) {
        #pragma unroll
        for (int i2 = 0; i2 < 2; ++i2) {
            asm volatile("" : "+v"(w1h[j][i2]));
            asm volatile("" : "+v"(w1x[j][i2]));
            asm volatile("" : "+v"(w2h[j][i2]));
            asm volatile("" : "+v"(w2i[j][i2]));
        }
    }

    // per-batch pointers
    const float* __restrict__ xb[NB];
    float* hsl1[NB]; float* hsl2[NB];
    #pragma unroll
    for (int bi = 0; bi < NB; ++bi) {
        xb[bi] = x + (size_t)(b0 + bi) * ROW_F;
        hsl1[bi] = &shh[wid][bi][0][0];
        hsl2[bi] = &shh[wid][bi][1][0];
    }

    // zero x pad slots (cols 11..15 of every row, both buffers, both batches)
    #pragma unroll
    for (int idx = 0; idx < CHUNK_T * ROW_PAD; idx += 64) {
        const int s = idx + lane;
        if ((s & 15) >= IN_DIM) {
            #pragma unroll
            for (int bi = 0; bi < NB; ++bi) {
                xlds[wid][bi][0][s] = 0.f;
                xlds[wid][bi][1][s] = 0.f;
            }
        }
    }

    // staging: source chunk float f -> padded slot (f/11)*16 + f%11.
    // f3 clamped to CHUNK_F-1 for BOTH load and store (extra lanes write a
    // duplicate of the correct value; no OOB - fixes R6 latent bug).
    const int f1i = lane, f2i = lane + 64;
    const int f3c = min(lane + 128, CHUNK_F - 1);
    const int p1 = (f1i / IN_DIM) * ROW_PAD + (f1i % IN_DIM);
    const int p2 = (f2i / IN_DIM) * ROW_PAD + (f2i % IN_DIM);
    const int p3 = (f3c / IN_DIM) * ROW_PAD + (f3c % IN_DIM);

    // prologue: global-load chunk 0 for both batches
    float gl0[NB], gl1[NB], gl2[NB];
    #pragma unroll
    for (int bi = 0; bi < NB; ++bi) {
        gl0[bi] = xb[bi][f1i];
        gl1[bi] = xb[bi][f2i];
        gl2[bi] = xb[bi][f3c];
    }

    float c1[NB], c2[NB], h2v[NB], ssum[NB];
    v2f h1a[NB], h1b[NB], h2a[NB], h2b[NB];   // carried h quartets
    #pragma unroll
    for (int bi = 0; bi < NB; ++bi) {
        c1[bi] = 0.f; c2[bi] = 0.f; h2v[bi] = 0.f; ssum[bi] = 0.f;
        h1a[bi] = (v2f){0.f, 0.f}; h1b[bi] = (v2f){0.f, 0.f};
        h2a[bi] = (v2f){0.f, 0.f}; h2b[bi] = (v2f){0.f, 0.f};
    }

    const int xoff = 4 * gt;            // quartet offset within a padded row

    for (int ck = 0; ck < N_CHUNK; ++ck) {
        float* xbuf[NB];
        #pragma unroll
        for (int bi = 0; bi < NB; ++bi) {
            xbuf[bi] = &xlds[wid][bi][ck & 1][0];
            xbuf[bi][p1] = gl0[bi];
            xbuf[bi][p2] = gl1[bi];
            xbuf[bi][p3] = gl2[bi];
        }
        if (ck + 1 < N_CHUNK) {
            const int base = (ck + 1) * CHUNK_F;
            #pragma unroll
            for (int bi = 0; bi < NB; ++bi) {
                gl0[bi] = xb[bi][base + f1i];
                gl1[bi] = xb[bi][base + f2i];
                gl2[bi] = xb[bi][base + f3c];
            }
        }

        #pragma unroll
        for (int t2 = 0; t2 < CHUNK_T; ++t2) {
            // ---- L2 recurrent partials first (prev-step h2, chain-free) ----
            v2f e0[NB], e1[NB], e2[NB], e3[NB];
            #pragma unroll
            for (int bi = 0; bi < NB; ++bi) {
                e0[bi] = pk_fma(w2h[0][0], h2a[bi], (v2f){bb2, 0.f});
                e0[bi] = pk_fma(w2h[0][1], h2b[bi], e0[bi]);
                e1[bi] = pk_fma(w2h[1][0], h2a[bi], (v2f){0.f, 0.f});
                e1[bi] = pk_fma(w2h[1][1], h2b[bi], e1[bi]);
                e2[bi] = pk_fma(w2h[2][0], h2a[bi], (v2f){0.f, 0.f});
                e2[bi] = pk_fma(w2h[2][1], h2b[bi], e2[bi]);
                e3[bi] = pk_fma(w2h[3][0], h2a[bi], (v2f){0.f, 0.f});
                e3[bi] = pk_fma(w2h[3][1], h2b[bi], e3[bi]);
            }

            // ---- L1: x quartet (1 b128) + recurrent quartet partials ----
            float g1v[NB];
            #pragma unroll
            for (int bi = 0; bi < NB; ++bi) {
                const v4f xq = *(const v4f*)(xbuf[bi] + t2 * ROW_PAD + xoff);
                const v2f x01 = (v2f){xq.x, xq.y};
                const v2f x23 = (v2f){xq.z, xq.w};
                v2f d0 = pk_fma(w1h[0][0], h1a[bi], (v2f){bb1, 0.f});
                d0 = pk_fma(w1h[0][1], h1b[bi], d0);
                d0 = pk_fma(w1x[0][0], x01, d0);
                d0 = pk_fma(w1x[0][1], x23, d0);
                v2f d1 = pk_fma(w1h[1][0], h1a[bi], (v2f){0.f, 0.f});
                d1 = pk_fma(w1h[1][1], h1b[bi], d1);
                d1 = pk_fma(w1x[1][0], x01, d1);
                d1 = pk_fma(w1x[1][1], x23, d1);
                v2f d2 = pk_fma(w1h[2][0], h1a[bi], (v2f){0.f, 0.f});
                d2 = pk_fma(w1h[2][1], h1b[bi], d2);
                d2 = pk_fma(w1x[2][0], x01, d2);
                d2 = pk_fma(w1x[2][1], x23, d2);
                v2f d3 = pk_fma(w1h[3][0], h1a[bi], (v2f){0.f, 0.f});
                d3 = pk_fma(w1h[3][1], h1b[bi], d3);
                d3 = pk_fma(w1x[3][0], x01, d3);
                d3 = pk_fma(w1x[3][1], x23, d3);
                const float u0 = d0.x + d0.y;
                const float u1 = d1.x + d1.y;
                const float u2 = d2.x + d2.y;
                const float u3 = d3.x + d3.y;
                g1v[bi] = u0 + qperm<0xB1>(u1) + qperm<0x4E>(u2) + qperm<0x1B>(u3);
            }

            // ---- L1 act + h1 slab transpose (write b32 / read b128) ----
            #pragma unroll
            for (int bi = 0; bi < NB; ++bi) {
                float h1v;
                ACT_STEP(g1v[bi], c1[bi], h1v);
                hsl1[bi][r] = h1v;
            }
            #pragma unroll
            for (int bi = 0; bi < NB; ++bi) {
                const v4f h1q = *(const v4f*)(hsl1[bi] + xoff);
                h1a[bi] = (v2f){h1q.x, h1q.y};
                h1b[bi] = (v2f){h1q.z, h1q.w};
            }

            // ---- L2 input partials on fresh h1, exchange, act ----
            float g2v[NB];
            #pragma unroll
            for (int bi = 0; bi < NB; ++bi) {
                e0[bi] = pk_fma(w2i[0][0], h1a[bi], e0[bi]);
                e0[bi] = pk_fma(w2i[0][1], h1b[bi], e0[bi]);
                e1[bi] = pk_fma(w2i[1][0], h1a[bi], e1[bi]);
                e1[bi] = pk_fma(w2i[1][1], h1b[bi], e1[bi]);
                e2[bi] = pk_fma(w2i[2][0], h1a[bi], e2[bi]);
                e2[bi] = pk_fma(w2i[2][1], h1b[bi], e2[bi]);
                e3[bi] = pk_fma(w2i[3][0], h1a[bi], e3[bi]);
                e3[bi] = pk_fma(w2i[3][1], h1b[bi], e3[bi]);
                const float v0 = e0[bi].x + e0[bi].y;
                const float v1 = e1[bi].x + e1[bi].y;
                const float v2 = e2[bi].x + e2[bi].y;
                const float v3 = e3[bi].x + e3[bi].y;
                g2v[bi] = v0 + qperm<0xB1>(v1) + qperm<0x4E>(v2) + qperm<0x1B>(v3);
            }
            #pragma unroll
            for (int bi = 0; bi < NB; ++bi) {
                ACT_STEP(g2v[bi], c2[bi], h2v[bi]);
                hsl2[bi][r] = h2v[bi];
            }
            #pragma unroll
            for (int bi = 0; bi < NB; ++bi) {
                const v4f h2q = *(const v4f*)(hsl2[bi] + xoff);
                h2a[bi] = (v2f){h2q.x, h2q.y};
                h2b[bi] = (v2f){h2q.z, h2q.w};
                ssum[bi] += __builtin_amdgcn_exp2f(LOG2E * h2v[bi]);
            }
        }
    }

    // ---- epilogue per batch: time-softmax select + dense head ----
    #pragma unroll
    for (int bi = 0; bi < NB; ++bi) {
        const int b = b0 + bi;
        const float sv = __builtin_amdgcn_exp2f(LOG2E * h2v[bi]) / ssum[bi];

        float ssb[H_DIM];
        #pragma unroll
        for (int k = 0; k < H_DIM; ++k) ssb[k] = bcast_lane(sv, 4 * k);

        const int r8 = lane & 7;
        float acc1 = bd1[r8];
        #pragma unroll
        for (int k = 0; k < H_DIM; ++k)
            acc1 = __builtin_fmaf(Wd1[r8 * H_DIM + k], ssb[k], acc1);

        float d1s[8];
        #pragma unroll
        for (int j = 0; j < 8; ++j) d1s[j] = bcast_lane(acc1, j);

        float acc2 = bd2[r8];
        #pragma unroll
        for (int k = 0; k < 8; ++k)
            acc2 = __builtin_fmaf(Wd2[r8 * 8 + k], d1s[k], acc2);

        float d2s[8];
        #pragma unroll
        for (int j = 0; j < 8; ++j) d2s[j] = bcast_lane(acc2, j);

        float lg = 0.f;
        if (lane < 3) {
            lg = bd3[lane];
            #pragma unroll
            for (int k = 0; k < 8; ++k)
                lg = __builtin_fmaf(Wd3[lane * 8 + k], d2s[k], lg);
        }
        const float l0 = bcast_lane(lg, 0);
        const float l1 = bcast_lane(lg, 1);
        const float l2 = bcast_lane(lg, 2);
        const float mx = fmaxf(l0, fmaxf(l1, l2));
        const float e0 = __builtin_amdgcn_exp2f(LOG2E * (l0 - mx));
        const float e1 = __builtin_amdgcn_exp2f(LOG2E * (l1 - mx));
        const float e2 = __builtin_amdgcn_exp2f(LOG2E * (l2 - mx));
        const float inv = 1.0f / (e0 + e1 + e2);
        if (lane < 3) {
            const float ev = (lane == 0) ? e0 : ((lane == 1) ? e1 : e2);
            out[b * 3 + lane] = ev * inv;
        }
    }
}

extern "C" void kernel_launch(void* const* d_in, const int* in_sizes, int n_in,
                              void* d_out, int out_size, void* d_ws, size_t ws_size,
                              hipStream_t stream) {
    (void)in_sizes; (void)n_in; (void)out_size; (void)d_ws; (void)ws_size;
    const float* x    = (const float*)d_in[0];
    const float* Wih1 = (const float*)d_in[1];
    const float* Whh1 = (const float*)d_in[2];
    const float* bih1 = (const float*)d_in[3];
    const float* bhh1 = (const float*)d_in[4];
    const float* Wih2 = (const float*)d_in[5];
    const float* Whh2 = (const float*)d_in[6];
    const float* bih2 = (const float*)d_in[7];
    const float* bhh2 = (const float*)d_in[8];
    const float* Wd1  = (const float*)d_in[9];
    const float* bd1  = (const float*)d_in[10];
    const float* Wd2  = (const float*)d_in[11];
    const float* bd2  = (const float*)d_in[12];
    const float* Wd3  = (const float*)d_in[13];
    const float* bd3  = (const float*)d_in[14];

    lstm2_head<<<dim3(4096 / (4 * NB)), dim3(256), 0, stream>>>(
        x, Wih1, Whh1, bih1, bhh1, Wih2, Whh2, bih2, bhh2,
        Wd1, bd1, Wd2, bd2, Wd3, bd3, (float*)d_out);
}